// Round 3
// baseline (1198.288 us; speedup 1.0000x reference)
//
#include <hip/hip_runtime.h>
#include <math.h>

#define SD 68  // padded LDS row stride (floats); multiple of 4 for b128 alignment

// ---------------------------------------------------------------------------
// Generic 64x64-tile fp32 GEMM, C[M,N] = A[M,K] @ B[K,N], K=N=1024 fixed.
// qkv_mode=1: apply per-row mask and scatter into [B,H,S,HD] layout.
// qkv_mode=0: plain row-major store.
// ---------------------------------------------------------------------------
__global__ __launch_bounds__(256) void gemm64(
    const float* __restrict__ A, const float* __restrict__ B,
    float* __restrict__ C, const float* __restrict__ mask, const int qkv_mode)
{
    constexpr int N = 1024, Kd = 1024;
    __shared__ float As[16 * SD];  // transposed: As[k][m]
    __shared__ float Bs[16 * SD];  // Bs[k][n]
    const int t = threadIdx.x;
    const int m0 = blockIdx.y * 64, n0 = blockIdx.x * 64;
    const int ty = t >> 4, tx = t & 15;
    const int ar = t >> 2, akg = (t & 3) * 4;   // A staging: row, k-group (16x64: 1 f4/thread)
    const int bk = t >> 4, bng = (t & 15) * 4;  // B staging: k-row, n-group
    float acc[4][4] = {};

    for (int k0 = 0; k0 < Kd; k0 += 16) {
        __syncthreads();
        const float4 av = *(const float4*)(A + (size_t)(m0 + ar) * Kd + k0 + akg);
        const float4 bv = *(const float4*)(B + (size_t)(k0 + bk) * N + n0 + bng);
        As[(akg + 0) * SD + ar] = av.x;
        As[(akg + 1) * SD + ar] = av.y;
        As[(akg + 2) * SD + ar] = av.z;
        As[(akg + 3) * SD + ar] = av.w;
        *(float4*)(Bs + bk * SD + bng) = bv;
        __syncthreads();
#pragma unroll
        for (int k = 0; k < 16; k++) {
            const float4 a = *(const float4*)(As + k * SD + 4 * ty);
            const float4 b = *(const float4*)(Bs + k * SD + 4 * tx);
            const float aa[4] = {a.x, a.y, a.z, a.w};
            const float bb[4] = {b.x, b.y, b.z, b.w};
#pragma unroll
            for (int i = 0; i < 4; i++)
#pragma unroll
                for (int j = 0; j < 4; j++)
                    acc[i][j] += aa[i] * bb[j];
        }
    }

    if (qkv_mode) {
        const int h = blockIdx.x;  // n-tile == head (HD=64 tile never crosses a head)
#pragma unroll
        for (int i = 0; i < 4; i++) {
            const int m = m0 + 4 * ty + i;
            const int b = m >> 11, s = m & 2047;
            const float mv = mask[m];
            float4 o;
            o.x = acc[i][0] * mv; o.y = acc[i][1] * mv;
            o.z = acc[i][2] * mv; o.w = acc[i][3] * mv;
            *(float4*)(C + ((size_t)(b * 16 + h) * 2048 + s) * 64 + 4 * tx) = o;
        }
    } else {
#pragma unroll
        for (int i = 0; i < 4; i++) {
            float4 o;
            o.x = acc[i][0]; o.y = acc[i][1]; o.z = acc[i][2]; o.w = acc[i][3];
            *(float4*)(C + (size_t)(m0 + 4 * ty + i) * N + n0 + 4 * tx) = o;
        }
    }
}

// ---------------------------------------------------------------------------
// Flash-style attention over fp32 [B,H,S,HD] Q/K/V with key-indicator masking.
// Post-softmax ind_k mask + renorm == softmax restricted to unmasked keys
// (masked keys score exp(0)=1 in ref's softmax but cancel in the renorm),
// implemented as exclusion + online softmax; l==0 guard -> zero output.
// One block per (q-tile of 64, head, batch). 256 threads, 4x4 microtiles.
// ---------------------------------------------------------------------------
__global__ __launch_bounds__(256) void attn64(
    const float* __restrict__ Q, const float* __restrict__ K,
    const float* __restrict__ V, const float* __restrict__ indk,
    float* __restrict__ AO)
{
    __shared__ float Qs[64 * SD];
    __shared__ float Ks[64 * SD];
    __shared__ float Vs[64 * SD];
    __shared__ float Ps[64 * SD];
    __shared__ float indks[64];
    const int t = threadIdx.x;
    const int q0 = blockIdx.x * 64;
    const int h = blockIdx.y;
    const int b = blockIdx.z;
    const size_t base = (size_t)(b * 16 + h) * 2048 * 64;
    const float* Qb = Q + base;
    const float* Kb = K + base;
    const float* Vb = V + base;

    // Full-tile staging: 64 rows x 64 dims = 1024 float4s, 4 per thread.
    // lane-contiguous: addr(idx) = (idx>>4)*64 + (idx&15)*4 = idx*4  (coalesced)
#pragma unroll
    for (int u = 0; u < 4; u++) {
        const int idx = t + u * 256;
        const int r = idx >> 4, g = (idx & 15) * 4;
        *(float4*)(Qs + r * SD + g) = *(const float4*)(Qb + (q0 + r) * 64 + g);
    }

    const int ty = t >> 4, tx = t & 15;
    float acc[4][4] = {};
    float m_i[4] = {-INFINITY, -INFINITY, -INFINITY, -INFINITY};
    float l_i[4] = {0.f, 0.f, 0.f, 0.f};

    for (int k0 = 0; k0 < 2048; k0 += 64) {
        __syncthreads();  // previous PV readers done before overwriting Ks/Vs
#pragma unroll
        for (int u = 0; u < 4; u++) {
            const int idx = t + u * 256;
            const int r = idx >> 4, g = (idx & 15) * 4;
            *(float4*)(Ks + r * SD + g) = *(const float4*)(Kb + (k0 + r) * 64 + g);
            *(float4*)(Vs + r * SD + g) = *(const float4*)(Vb + (k0 + r) * 64 + g);
        }
        if (t < 64) indks[t] = indk[b * 2048 + k0 + t];
        __syncthreads();

        // scores: s[i][j] = dot(Q row 4ty+i, K row tx+16j)
        float s[4][4] = {};
#pragma unroll
        for (int d = 0; d < 64; d += 4) {
            float qa[4][4], ka[4][4];
#pragma unroll
            for (int i = 0; i < 4; i++) {
                const float4 qv = *(const float4*)(Qs + (4 * ty + i) * SD + d);
                qa[i][0] = qv.x; qa[i][1] = qv.y; qa[i][2] = qv.z; qa[i][3] = qv.w;
            }
#pragma unroll
            for (int j = 0; j < 4; j++) {
                // key = tx + 16j: 1-apart rows across lanes => 2-way (free) banks
                const float4 kv = *(const float4*)(Ks + (tx + 16 * j) * SD + d);
                ka[j][0] = kv.x; ka[j][1] = kv.y; ka[j][2] = kv.z; ka[j][3] = kv.w;
            }
#pragma unroll
            for (int i = 0; i < 4; i++)
#pragma unroll
                for (int j = 0; j < 4; j++)
#pragma unroll
                    for (int dd = 0; dd < 4; dd++)
                        s[i][j] += qa[i][dd] * ka[j][dd];
        }

        float msk[4];
#pragma unroll
        for (int j = 0; j < 4; j++) msk[j] = indks[tx + 16 * j];

#pragma unroll
        for (int i = 0; i < 4; i++) {
            float mx = -INFINITY;
#pragma unroll
            for (int j = 0; j < 4; j++) {
                s[i][j] *= 0.125f;  // 1/sqrt(64)
                if (msk[j] != 0.f) mx = fmaxf(mx, s[i][j]);
            }
#pragma unroll
            for (int off = 1; off < 16; off <<= 1)  // row group = 16 consecutive lanes
                mx = fmaxf(mx, __shfl_xor(mx, off));
            const float mnew = fmaxf(m_i[i], mx);
            const float alpha = (m_i[i] == -INFINITY) ? 0.f : __expf(m_i[i] - mnew);
            float rs = 0.f;
            float p[4];
#pragma unroll
            for (int j = 0; j < 4; j++) {
                p[j] = (msk[j] != 0.f) ? __expf(s[i][j] - mnew) : 0.f;
                rs += p[j];
            }
#pragma unroll
            for (int off = 1; off < 16; off <<= 1)
                rs += __shfl_xor(rs, off);
            l_i[i] = l_i[i] * alpha + rs;
            m_i[i] = mnew;
#pragma unroll
            for (int j = 0; j < 4; j++) acc[i][j] *= alpha;
#pragma unroll
            for (int j = 0; j < 4; j++) Ps[(4 * ty + i) * SD + tx + 16 * j] = p[j];
        }
        __syncthreads();  // Ps fully written before PV reads

        // PV: acc[i][j] += sum_k Ps[4ty+i][k] * Vs[k][4tx+j]
#pragma unroll
        for (int k = 0; k < 64; k += 4) {
            float pr[4][4], vr[4][4];
#pragma unroll
            for (int i = 0; i < 4; i++) {
                const float4 pv = *(const float4*)(Ps + (4 * ty + i) * SD + k);
                pr[i][0] = pv.x; pr[i][1] = pv.y; pr[i][2] = pv.z; pr[i][3] = pv.w;
            }
#pragma unroll
            for (int kk = 0; kk < 4; kk++) {
                const float4 vv = *(const float4*)(Vs + (k + kk) * SD + 4 * tx);
                vr[kk][0] = vv.x; vr[kk][1] = vv.y; vr[kk][2] = vv.z; vr[kk][3] = vv.w;
            }
#pragma unroll
            for (int i = 0; i < 4; i++)
#pragma unroll
                for (int j = 0; j < 4; j++)
#pragma unroll
                    for (int kk = 0; kk < 4; kk++)
                        acc[i][j] += pr[i][kk] * vr[kk][j];
        }
    }

#pragma unroll
    for (int i = 0; i < 4; i++) {
        const float inv = (l_i[i] > 0.f) ? 1.f / l_i[i] : 0.f;  // zero-row guard
        float4 o;
        o.x = acc[i][0] * inv; o.y = acc[i][1] * inv;
        o.z = acc[i][2] * inv; o.w = acc[i][3] * inv;
        *(float4*)(AO + ((size_t)(b * 2048 + q0 + 4 * ty + i)) * 1024 + h * 64 + 4 * tx) = o;
    }
}

// ---------------------------------------------------------------------------
extern "C" void kernel_launch(void* const* d_in, const int* in_sizes, int n_in,
                              void* d_out, int out_size, void* d_ws, size_t ws_size,
                              hipStream_t stream) {
    const float* q  = (const float*)d_in[0];
    const float* k  = (const float*)d_in[1];
    const float* v  = (const float*)d_in[2];
    const float* iq = (const float*)d_in[3];
    const float* ik = (const float*)d_in[4];
    const float* iv = (const float*)d_in[5];
    const float* Wq = (const float*)d_in[6];
    const float* Wk = (const float*)d_in[7];
    const float* Wv = (const float*)d_in[8];
    const float* Wo = (const float*)d_in[9];
    float* out = (float*)d_out;
    float* ws = (float*)d_ws;

    // workspace layout (floats): Q,K,V as [B,H,S,HD] (4M each), AO as [B,S,1024]
    float* Qw = ws;
    float* Kw = ws + 4194304;
    float* Vw = ws + 8388608;
    float* AO = ws + 12582912;  // total 64 MB

    const dim3 blk(256);
    const dim3 gproj(16, 64);  // N/64, M/64
    gemm64<<<gproj, blk, 0, stream>>>(q, Wq, Qw, iq, 1);
    gemm64<<<gproj, blk, 0, stream>>>(k, Wk, Kw, ik, 1);
    gemm64<<<gproj, blk, 0, stream>>>(v, Wv, Vw, iv, 1);
    attn64<<<dim3(32, 16, 2), blk, 0, stream>>>(Qw, Kw, Vw, ik, AO);
    gemm64<<<gproj, blk, 0, stream>>>(AO, Wo, out, nullptr, 0);
}

// Round 4
// 366.773 us; speedup vs baseline: 3.2671x; 3.2671x over previous
//
#include <hip/hip_runtime.h>
#include <math.h>

typedef __attribute__((ext_vector_type(8))) short bf16x8;
typedef __attribute__((ext_vector_type(4))) float f32x4;

__device__ __forceinline__ unsigned short f2b(float f) {
    union { float f; unsigned int u; } v; v.f = f;
    unsigned int u = v.u + 0x7FFFu + ((v.u >> 16) & 1u);  // RNE
    return (unsigned short)(u >> 16);
}

__device__ __forceinline__ f32x4 mfma16(bf16x8 a, bf16x8 b, f32x4 c) {
    return __builtin_amdgcn_mfma_f32_16x16x32_bf16(a, b, c, 0, 0, 0);
}

#define GST 72  // LDS row stride in shorts: 144B = 9*16B -> b128-aligned, frag reads conflict-free

// ---------------------------------------------------------------------------
// Projection GEMM: bf16-MFMA, C = mask-scatter(A[4096x1024]f32 @ B[1024x1024]f32)
// -> bf16 ws [B,H,S,HD]. BM=BN=64, BK=64. 256 thr = 4 waves (2x2), wave tile 32x32.
// ---------------------------------------------------------------------------
__global__ __launch_bounds__(256, 4) void gemm_proj(
    const float* __restrict__ A, const float* __restrict__ B,
    unsigned short* __restrict__ Cw, const float* __restrict__ mask)
{
    __shared__ __align__(16) short As[64 * GST];
    __shared__ __align__(16) short Bs[64 * GST];
    __shared__ float maskL[64];
    const int t = threadIdx.x;
    const int w = t >> 6, lane = t & 63, l15 = lane & 15, quad = lane >> 4;
    const int wr = w >> 1, wc = w & 1;
    const int n0 = blockIdx.x * 64, m0 = blockIdx.y * 64;
    const int h = blockIdx.x;  // BN=64 == head dim
    if (t < 64) maskL[t] = mask[m0 + t];

    f32x4 zero4 = {0.f, 0.f, 0.f, 0.f};
    f32x4 acc[2][2];
    acc[0][0] = zero4; acc[0][1] = zero4; acc[1][0] = zero4; acc[1][1] = zero4;

    for (int k0 = 0; k0 < 1024; k0 += 64) {
        __syncthreads();
        // A staging: natural [m][k], cvt fp32->bf16
#pragma unroll
        for (int i = 0; i < 4; ++i) {
            const int idx = t + 256 * i;
            const int m = idx >> 4, kg = (idx & 15) * 4;
            const float4 av = *(const float4*)&A[(size_t)(m0 + m) * 1024 + k0 + kg];
            ushort4 o; o.x = f2b(av.x); o.y = f2b(av.y); o.z = f2b(av.z); o.w = f2b(av.w);
            *(ushort4*)&As[m * GST + kg] = o;
        }
        // B staging transposed: Bs[n][k]; each thread gathers 4 k's of one n
#pragma unroll
        for (int i = 0; i < 4; ++i) {
            const int n = t & 63, kq = (t >> 6) + 4 * i;
            ushort4 o;
            o.x = f2b(B[(size_t)(k0 + 4 * kq + 0) * 1024 + n0 + n]);
            o.y = f2b(B[(size_t)(k0 + 4 * kq + 1) * 1024 + n0 + n]);
            o.z = f2b(B[(size_t)(k0 + 4 * kq + 2) * 1024 + n0 + n]);
            o.w = f2b(B[(size_t)(k0 + 4 * kq + 3) * 1024 + n0 + n]);
            *(ushort4*)&Bs[n * GST + 4 * kq] = o;
        }
        __syncthreads();
#pragma unroll
        for (int ks = 0; ks < 2; ++ks) {
            bf16x8 af[2], bfr[2];
            af[0]  = *(const bf16x8*)&As[(32 * wr      + l15) * GST + 32 * ks + 8 * quad];
            af[1]  = *(const bf16x8*)&As[(32 * wr + 16 + l15) * GST + 32 * ks + 8 * quad];
            bfr[0] = *(const bf16x8*)&Bs[(32 * wc      + l15) * GST + 32 * ks + 8 * quad];
            bfr[1] = *(const bf16x8*)&Bs[(32 * wc + 16 + l15) * GST + 32 * ks + 8 * quad];
            acc[0][0] = mfma16(af[0], bfr[0], acc[0][0]);
            acc[0][1] = mfma16(af[0], bfr[1], acc[0][1]);
            acc[1][0] = mfma16(af[1], bfr[0], acc[1][0]);
            acc[1][1] = mfma16(af[1], bfr[1], acc[1][1]);
        }
    }
    // epilogue: C/D layout col=l15, row=4*quad+reg; mask + scatter bf16
#pragma unroll
    for (int mi = 0; mi < 2; ++mi)
#pragma unroll
        for (int nj = 0; nj < 2; ++nj)
#pragma unroll
            for (int reg = 0; reg < 4; ++reg) {
                const int mloc = 32 * wr + 16 * mi + 4 * quad + reg;
                const int m = m0 + mloc;
                const int bb = m >> 11, s = m & 2047;
                const int hd = 32 * wc + 16 * nj + l15;
                const float val = acc[mi][nj][reg] * maskL[mloc];
                Cw[((size_t)(bb * 16 + h) * 2048 + s) * 64 + hd] = f2b(val);
            }
}

// ---------------------------------------------------------------------------
// Output GEMM: bf16-MFMA, out[4096x1024]f32 = AO[4096x1024]bf16 @ Wo[1024x1024]f32
// ---------------------------------------------------------------------------
__global__ __launch_bounds__(256, 4) void gemm_out(
    const unsigned short* __restrict__ A, const float* __restrict__ B,
    float* __restrict__ C)
{
    __shared__ __align__(16) short As[64 * GST];
    __shared__ __align__(16) short Bs[64 * GST];
    const int t = threadIdx.x;
    const int w = t >> 6, lane = t & 63, l15 = lane & 15, quad = lane >> 4;
    const int wr = w >> 1, wc = w & 1;
    const int n0 = blockIdx.x * 64, m0 = blockIdx.y * 64;

    f32x4 zero4 = {0.f, 0.f, 0.f, 0.f};
    f32x4 acc[2][2];
    acc[0][0] = zero4; acc[0][1] = zero4; acc[1][0] = zero4; acc[1][1] = zero4;

    for (int k0 = 0; k0 < 1024; k0 += 64) {
        __syncthreads();
#pragma unroll
        for (int i = 0; i < 4; ++i) {
            const int idx = t + 256 * i;
            const int m = idx >> 4, kg = (idx & 15) * 4;
            *(ushort4*)&As[m * GST + kg] =
                *(const ushort4*)&A[(size_t)(m0 + m) * 1024 + k0 + kg];
        }
#pragma unroll
        for (int i = 0; i < 4; ++i) {
            const int n = t & 63, kq = (t >> 6) + 4 * i;
            ushort4 o;
            o.x = f2b(B[(size_t)(k0 + 4 * kq + 0) * 1024 + n0 + n]);
            o.y = f2b(B[(size_t)(k0 + 4 * kq + 1) * 1024 + n0 + n]);
            o.z = f2b(B[(size_t)(k0 + 4 * kq + 2) * 1024 + n0 + n]);
            o.w = f2b(B[(size_t)(k0 + 4 * kq + 3) * 1024 + n0 + n]);
            *(ushort4*)&Bs[n * GST + 4 * kq] = o;
        }
        __syncthreads();
#pragma unroll
        for (int ks = 0; ks < 2; ++ks) {
            bf16x8 af[2], bfr[2];
            af[0]  = *(const bf16x8*)&As[(32 * wr      + l15) * GST + 32 * ks + 8 * quad];
            af[1]  = *(const bf16x8*)&As[(32 * wr + 16 + l15) * GST + 32 * ks + 8 * quad];
            bfr[0] = *(const bf16x8*)&Bs[(32 * wc      + l15) * GST + 32 * ks + 8 * quad];
            bfr[1] = *(const bf16x8*)&Bs[(32 * wc + 16 + l15) * GST + 32 * ks + 8 * quad];
            acc[0][0] = mfma16(af[0], bfr[0], acc[0][0]);
            acc[0][1] = mfma16(af[0], bfr[1], acc[0][1]);
            acc[1][0] = mfma16(af[1], bfr[0], acc[1][0]);
            acc[1][1] = mfma16(af[1], bfr[1], acc[1][1]);
        }
    }
#pragma unroll
    for (int mi = 0; mi < 2; ++mi)
#pragma unroll
        for (int nj = 0; nj < 2; ++nj)
#pragma unroll
            for (int reg = 0; reg < 4; ++reg) {
                const int mloc = 32 * wr + 16 * mi + 4 * quad + reg;
                C[(size_t)(m0 + mloc) * 1024 + n0 + 32 * wc + 16 * nj + l15] =
                    acc[mi][nj][reg];
            }
}

// ---------------------------------------------------------------------------
// MFMA flash attention. bf16 Q/K/V ws [B,H,S,HD]; ind_k exclusion + online
// softmax (fp32 state) == ref's post-softmax mask + renorm; l==0 -> 0.
// 512 thr = 8 waves; Q-tile 128 (16 q-rows/wave); 64-key chunks.
// ---------------------------------------------------------------------------
__global__ __launch_bounds__(512, 4) void attn_mfma(
    const unsigned short* __restrict__ Qw, const unsigned short* __restrict__ Kw,
    const unsigned short* __restrict__ Vw, const float* __restrict__ indk,
    unsigned short* __restrict__ AO)
{
    __shared__ __align__(16) short Qs[128 * GST];
    __shared__ __align__(16) short Ks[64 * GST];
    __shared__ __align__(16) short Vt[64 * GST];   // transposed: Vt[dim][key]
    __shared__ __align__(16) short Ps[128 * GST];
    __shared__ float indks[64];
    const int t = threadIdx.x;
    const int w = t >> 6, lane = t & 63, l15 = lane & 15, quad = lane >> 4;
    const int q0 = blockIdx.x * 128;
    const int h = blockIdx.y, b = blockIdx.z;
    const size_t base = (size_t)(b * 16 + h) * (2048 * 64);
    const unsigned short* Qb = Qw + base + (size_t)q0 * 64;
    const unsigned short* Kb = Kw + base;
    const unsigned short* Vb = Vw + base;

    // stage Q tile (128x64): 2048 ushort4 / 512 thr = 4 each
#pragma unroll
    for (int i = 0; i < 4; ++i) {
        const int idx = t + 512 * i;
        const int r = idx >> 4, dg = (idx & 15) * 4;
        *(ushort4*)&Qs[r * GST + dg] = *(const ushort4*)&Qb[r * 64 + dg];
    }

    f32x4 zero4 = {0.f, 0.f, 0.f, 0.f};
    f32x4 oacc[4];
    oacc[0] = zero4; oacc[1] = zero4; oacc[2] = zero4; oacc[3] = zero4;
    float m_i[4] = {-INFINITY, -INFINITY, -INFINITY, -INFINITY};
    float l_i[4] = {0.f, 0.f, 0.f, 0.f};

    for (int k0 = 0; k0 < 2048; k0 += 64) {
        __syncthreads();  // all waves done with previous Ks/Vt
#pragma unroll
        for (int i = 0; i < 2; ++i) {
            const int idx = t + 512 * i;
            // K: row-major (coalesced load, conflict-free b64 write)
            const int r = idx >> 4, dg = (idx & 15) * 4;
            *(ushort4*)&Ks[r * GST + dg] = *(const ushort4*)&Kb[(size_t)(k0 + r) * 64 + dg];
            // V: key-major lane mapping -> transpose writes are 2-way (free)
            const int key = idx & 63, dq = idx >> 6;
            const ushort4 vv = *(const ushort4*)&Vb[(size_t)(k0 + key) * 64 + 4 * dq];
            Vt[(4 * dq + 0) * GST + key] = vv.x;
            Vt[(4 * dq + 1) * GST + key] = vv.y;
            Vt[(4 * dq + 2) * GST + key] = vv.z;
            Vt[(4 * dq + 3) * GST + key] = vv.w;
        }
        if (t < 64) indks[t] = indk[b * 2048 + k0 + t];
        __syncthreads();

        // S = Q K^T : A-frag rows = q, B-frag "n" = key (Ks rows), k = dim
        f32x4 sacc[4];
        sacc[0] = zero4; sacc[1] = zero4; sacc[2] = zero4; sacc[3] = zero4;
#pragma unroll
        for (int ks = 0; ks < 2; ++ks) {
            const bf16x8 aq = *(const bf16x8*)&Qs[(16 * w + l15) * GST + 32 * ks + 8 * quad];
#pragma unroll
            for (int nj = 0; nj < 4; ++nj) {
                const bf16x8 bk = *(const bf16x8*)&Ks[(16 * nj + l15) * GST + 32 * ks + 8 * quad];
                sacc[nj] = mfma16(aq, bk, sacc[nj]);
            }
        }

        float msk[4];
#pragma unroll
        for (int nj = 0; nj < 4; ++nj) msk[nj] = indks[16 * nj + l15];

        // online softmax per row (row = 4*quad + reg within wave's 16-row tile)
#pragma unroll
        for (int reg = 0; reg < 4; ++reg) {
            float sv[4];
            float mx = -INFINITY;
#pragma unroll
            for (int nj = 0; nj < 4; ++nj) {
                sv[nj] = sacc[nj][reg] * 0.125f;  // 1/sqrt(64)
                if (msk[nj] != 0.f) mx = fmaxf(mx, sv[nj]);
            }
            mx = fmaxf(mx, __shfl_xor(mx, 1));
            mx = fmaxf(mx, __shfl_xor(mx, 2));
            mx = fmaxf(mx, __shfl_xor(mx, 4));
            mx = fmaxf(mx, __shfl_xor(mx, 8));
            const float mold = m_i[reg];
            const float mnew = fmaxf(mold, mx);
            const float alpha = (mold == -INFINITY) ? 0.f : __expf(mold - mnew);
            float p[4], rs = 0.f;
#pragma unroll
            for (int nj = 0; nj < 4; ++nj) {
                p[nj] = (msk[nj] != 0.f) ? __expf(sv[nj] - mnew) : 0.f;
                rs += p[nj];
            }
            rs += __shfl_xor(rs, 1);
            rs += __shfl_xor(rs, 2);
            rs += __shfl_xor(rs, 4);
            rs += __shfl_xor(rs, 8);
            l_i[reg] = l_i[reg] * alpha + rs;
            m_i[reg] = mnew;
            const int prow = 16 * w + 4 * quad + reg;
#pragma unroll
            for (int nj = 0; nj < 4; ++nj) {
                oacc[nj][reg] *= alpha;
                Ps[prow * GST + 16 * nj + l15] = (short)f2b(p[nj]);
            }
        }

        // O += P V : A-frag = own wave's Ps rows (same-wave LDS, in-order), B = Vt
#pragma unroll
        for (int ks = 0; ks < 2; ++ks) {
            const bf16x8 pa = *(const bf16x8*)&Ps[(16 * w + l15) * GST + 32 * ks + 8 * quad];
#pragma unroll
            for (int nj = 0; nj < 4; ++nj) {
                const bf16x8 vb = *(const bf16x8*)&Vt[(16 * nj + l15) * GST + 32 * ks + 8 * quad];
                oacc[nj] = mfma16(pa, vb, oacc[nj]);
            }
        }
    }

    float inv[4];
#pragma unroll
    for (int reg = 0; reg < 4; ++reg)
        inv[reg] = (l_i[reg] > 0.f) ? 1.f / l_i[reg] : 0.f;  // zero-row guard
#pragma unroll
    for (int nj = 0; nj < 4; ++nj)
#pragma unroll
        for (int reg = 0; reg < 4; ++reg) {
            const int row = q0 + 16 * w + 4 * quad + reg;
            AO[(size_t)(b * 2048 + row) * 1024 + h * 64 + 16 * nj + l15] =
                f2b(oacc[nj][reg] * inv[reg]);
        }
}

// ---------------------------------------------------------------------------
extern "C" void kernel_launch(void* const* d_in, const int* in_sizes, int n_in,
                              void* d_out, int out_size, void* d_ws, size_t ws_size,
                              hipStream_t stream) {
    const float* q  = (const float*)d_in[0];
    const float* k  = (const float*)d_in[1];
    const float* v  = (const float*)d_in[2];
    const float* iq = (const float*)d_in[3];
    const float* ik = (const float*)d_in[4];
    const float* iv = (const float*)d_in[5];
    const float* Wq = (const float*)d_in[6];
    const float* Wk = (const float*)d_in[7];
    const float* Wv = (const float*)d_in[8];
    const float* Wo = (const float*)d_in[9];
    float* out = (float*)d_out;
    unsigned short* ws = (unsigned short*)d_ws;

    // ws layout (ushorts): Qw,Kw,Vw bf16 [B,H,S,HD] (4M each), AO bf16 [4096,1024]
    unsigned short* Qw = ws;
    unsigned short* Kw = ws + 4194304;
    unsigned short* Vw = ws + 8388608;
    unsigned short* AO = ws + 12582912;  // total 33.5 MB

    const dim3 gg(16, 64);
    gemm_proj<<<gg, dim3(256), 0, stream>>>(q, Wq, Qw, iq);
    gemm_proj<<<gg, dim3(256), 0, stream>>>(k, Wk, Kw, ik);
    gemm_proj<<<gg, dim3(256), 0, stream>>>(v, Wv, Vw, iv);
    attn_mfma<<<dim3(16, 16, 2), dim3(512), 0, stream>>>(Qw, Kw, Vw, ik, AO);
    gemm_out<<<gg, dim3(256), 0, stream>>>(AO, Wo, out);
}

// Round 5
// 345.051 us; speedup vs baseline: 3.4728x; 1.0630x over previous
//
#include <hip/hip_runtime.h>
#include <math.h>

typedef __attribute__((ext_vector_type(8))) short bf16x8;
typedef __attribute__((ext_vector_type(4))) float f32x4;

__device__ __forceinline__ unsigned short f2b(float f) {
    union { float f; unsigned int u; } v; v.f = f;
    unsigned int u = v.u + 0x7FFFu + ((v.u >> 16) & 1u);  // RNE
    return (unsigned short)(u >> 16);
}

__device__ __forceinline__ f32x4 mfma16(bf16x8 a, bf16x8 b, f32x4 c) {
    return __builtin_amdgcn_mfma_f32_16x16x32_bf16(a, b, c, 0, 0, 0);
}

// async global->LDS, 16B per lane; LDS dest = wave-uniform base + lane*16
__device__ __forceinline__ void async_ld16(void* l, const void* g) {
    __builtin_amdgcn_global_load_lds(
        (__attribute__((address_space(1))) void*)g,
        (__attribute__((address_space(3))) void*)l, 16, 0, 0);
}

// ---------------------------------------------------------------------------
// fp32 -> bf16 elementwise convert (n divisible by 1024)
// ---------------------------------------------------------------------------
__global__ __launch_bounds__(256) void cvt_bf16(
    const float* __restrict__ in, unsigned short* __restrict__ out)
{
    const int i = (blockIdx.x * 256 + threadIdx.x) * 4;
    const float4 v = *(const float4*)(in + i);
    ushort4 o; o.x = f2b(v.x); o.y = f2b(v.y); o.z = f2b(v.z); o.w = f2b(v.w);
    *(ushort4*)(out + i) = o;
}

// ---------------------------------------------------------------------------
// Convert + transpose 1024x1024 W (row-major [K][N]) -> bf16 Wt [N][K].
// grid (16,16,4): z selects which W. 64x64 tiles.
// ---------------------------------------------------------------------------
__global__ __launch_bounds__(256) void cvt_tr(
    const float* __restrict__ W0, const float* __restrict__ W1,
    const float* __restrict__ W2, const float* __restrict__ W3,
    unsigned short* __restrict__ T0, unsigned short* __restrict__ T1,
    unsigned short* __restrict__ T2, unsigned short* __restrict__ T3)
{
    const int z = blockIdx.z;
    const float* W = (z == 0) ? W0 : (z == 1) ? W1 : (z == 2) ? W2 : W3;
    unsigned short* T = (z == 0) ? T0 : (z == 1) ? T1 : (z == 2) ? T2 : T3;
    __shared__ short Ls[64 * 65];
    const int t = threadIdx.x;
    const int k0 = blockIdx.x * 64, n0 = blockIdx.y * 64;
#pragma unroll
    for (int ii = 0; ii < 4; ++ii) {
        const int kl = (t >> 4) + 16 * ii, nl = (t & 15) * 4;
        const float4 v = *(const float4*)&W[(size_t)(k0 + kl) * 1024 + n0 + nl];
        Ls[kl * 65 + nl + 0] = (short)f2b(v.x);
        Ls[kl * 65 + nl + 1] = (short)f2b(v.y);
        Ls[kl * 65 + nl + 2] = (short)f2b(v.z);
        Ls[kl * 65 + nl + 3] = (short)f2b(v.w);
    }
    __syncthreads();
#pragma unroll
    for (int ii = 0; ii < 4; ++ii) {
        const int nl = (t >> 4) + 16 * ii, kl = (t & 15) * 4;
        ushort4 o;
        o.x = (unsigned short)Ls[(kl + 0) * 65 + nl];
        o.y = (unsigned short)Ls[(kl + 1) * 65 + nl];
        o.z = (unsigned short)Ls[(kl + 2) * 65 + nl];
        o.w = (unsigned short)Ls[(kl + 3) * 65 + nl];
        *(ushort4*)&T[(size_t)(n0 + nl) * 1024 + k0 + kl] = o;
    }
}

// ---------------------------------------------------------------------------
// m97-style bf16 GEMM: C[M,N] = A[M,1024] @ Bt[N,1024]^T.  BM=BN=128, BK=32.
// 256 thr = 4 waves (2x2 of 64x64), 4x4 mfma_16x16x32 per wave per iter.
// global_load_lds width-16 staging, unpadded LDS (layout = staging order).
// mode 1: mask + scatter bf16 [B,H,S,HD].  mode 0: fp32 row-major store.
// ---------------------------------------------------------------------------
template <int MODE>
__global__ __launch_bounds__(256) void gemm128(
    const unsigned short* __restrict__ A, const unsigned short* __restrict__ Bt,
    void* __restrict__ Cp, const float* __restrict__ mask)
{
    __shared__ __align__(16) short As[128 * 32];
    __shared__ __align__(16) short Bs[128 * 32];
    __shared__ float maskL[128];
    const int t = threadIdx.x;
    const int w = t >> 6, lane = t & 63, l15 = lane & 15, quad = lane >> 4;
    const int wr = w >> 1, wc = w & 1;
    const int n0 = blockIdx.x * 128, m0 = blockIdx.y * 128;
    if (MODE == 1 && t < 128) maskL[t] = mask[m0 + t];

    const int srow = lane >> 2;           // staging row within 16-row group
    const int soff = (lane & 3) * 8;      // k-offset in shorts (16B granules)

    f32x4 zero4 = {0.f, 0.f, 0.f, 0.f};
    f32x4 acc[4][4];
#pragma unroll
    for (int i = 0; i < 4; ++i)
#pragma unroll
        for (int j = 0; j < 4; ++j) acc[i][j] = zero4;

    for (int k0 = 0; k0 < 1024; k0 += 32) {
        __syncthreads();
#pragma unroll
        for (int i = 0; i < 2; ++i) {
            const int r = 16 * (2 * w + i);
            async_ld16(As + r * 32, A + (size_t)(m0 + r + srow) * 1024 + k0 + soff);
            async_ld16(Bs + r * 32, Bt + (size_t)(n0 + r + srow) * 1024 + k0 + soff);
        }
        __syncthreads();
        bf16x8 af[4], bfr[4];
#pragma unroll
        for (int i = 0; i < 4; ++i)
            af[i] = *(const bf16x8*)&As[(64 * wr + 16 * i + l15) * 32 + 8 * quad];
#pragma unroll
        for (int j = 0; j < 4; ++j)
            bfr[j] = *(const bf16x8*)&Bs[(64 * wc + 16 * j + l15) * 32 + 8 * quad];
#pragma unroll
        for (int i = 0; i < 4; ++i)
#pragma unroll
            for (int j = 0; j < 4; ++j)
                acc[i][j] = mfma16(af[i], bfr[j], acc[i][j]);
    }

    if (MODE == 1) {
        unsigned short* Cw = (unsigned short*)Cp;
        const int h = 2 * blockIdx.x + wc;  // 64-col wave tile == one head
#pragma unroll
        for (int i = 0; i < 4; ++i)
#pragma unroll
            for (int j = 0; j < 4; ++j)
#pragma unroll
                for (int reg = 0; reg < 4; ++reg) {
                    const int mloc = 64 * wr + 16 * i + 4 * quad + reg;
                    const int m = m0 + mloc;
                    const int bb = m >> 11, s = m & 2047;
                    const int hd = 16 * j + l15;
                    Cw[((size_t)(bb * 16 + h) * 2048 + s) * 64 + hd] =
                        f2b(acc[i][j][reg] * maskL[mloc]);
                }
    } else {
        float* C = (float*)Cp;
#pragma unroll
        for (int i = 0; i < 4; ++i)
#pragma unroll
            for (int j = 0; j < 4; ++j)
#pragma unroll
                for (int reg = 0; reg < 4; ++reg) {
                    const int m = m0 + 64 * wr + 16 * i + 4 * quad + reg;
                    const int n = n0 + 64 * wc + 16 * j + l15;
                    C[(size_t)m * 1024 + n] = acc[i][j][reg];
                }
    }
}

#define GST 72  // attn LDS row stride (shorts): 144B, b128-aligned

// ---------------------------------------------------------------------------
// MFMA flash attention (unchanged from round 4 — passed).
// ---------------------------------------------------------------------------
__global__ __launch_bounds__(512, 4) void attn_mfma(
    const unsigned short* __restrict__ Qw, const unsigned short* __restrict__ Kw,
    const unsigned short* __restrict__ Vw, const float* __restrict__ indk,
    unsigned short* __restrict__ AO)
{
    __shared__ __align__(16) short Qs[128 * GST];
    __shared__ __align__(16) short Ks[64 * GST];
    __shared__ __align__(16) short Vt[64 * GST];
    __shared__ __align__(16) short Ps[128 * GST];
    __shared__ float indks[64];
    const int t = threadIdx.x;
    const int w = t >> 6, lane = t & 63, l15 = lane & 15, quad = lane >> 4;
    const int q0 = blockIdx.x * 128;
    const int h = blockIdx.y, b = blockIdx.z;
    const size_t base = (size_t)(b * 16 + h) * (2048 * 64);
    const unsigned short* Qb = Qw + base + (size_t)q0 * 64;
    const unsigned short* Kb = Kw + base;
    const unsigned short* Vb = Vw + base;

#pragma unroll
    for (int i = 0; i < 4; ++i) {
        const int idx = t + 512 * i;
        const int r = idx >> 4, dg = (idx & 15) * 4;
        *(ushort4*)&Qs[r * GST + dg] = *(const ushort4*)&Qb[r * 64 + dg];
    }

    f32x4 zero4 = {0.f, 0.f, 0.f, 0.f};
    f32x4 oacc[4];
    oacc[0] = zero4; oacc[1] = zero4; oacc[2] = zero4; oacc[3] = zero4;
    float m_i[4] = {-INFINITY, -INFINITY, -INFINITY, -INFINITY};
    float l_i[4] = {0.f, 0.f, 0.f, 0.f};

    for (int k0 = 0; k0 < 2048; k0 += 64) {
        __syncthreads();
#pragma unroll
        for (int i = 0; i < 2; ++i) {
            const int idx = t + 512 * i;
            const int r = idx >> 4, dg = (idx & 15) * 4;
            *(ushort4*)&Ks[r * GST + dg] = *(const ushort4*)&Kb[(size_t)(k0 + r) * 64 + dg];
            const int key = idx & 63, dq = idx >> 6;
            const ushort4 vv = *(const ushort4*)&Vb[(size_t)(k0 + key) * 64 + 4 * dq];
            Vt[(4 * dq + 0) * GST + key] = vv.x;
            Vt[(4 * dq + 1) * GST + key] = vv.y;
            Vt[(4 * dq + 2) * GST + key] = vv.z;
            Vt[(4 * dq + 3) * GST + key] = vv.w;
        }
        if (t < 64) indks[t] = indk[b * 2048 + k0 + t];
        __syncthreads();

        f32x4 sacc[4];
        sacc[0] = zero4; sacc[1] = zero4; sacc[2] = zero4; sacc[3] = zero4;
#pragma unroll
        for (int ks = 0; ks < 2; ++ks) {
            const bf16x8 aq = *(const bf16x8*)&Qs[(16 * w + l15) * GST + 32 * ks + 8 * quad];
#pragma unroll
            for (int nj = 0; nj < 4; ++nj) {
                const bf16x8 bk = *(const bf16x8*)&Ks[(16 * nj + l15) * GST + 32 * ks + 8 * quad];
                sacc[nj] = mfma16(aq, bk, sacc[nj]);
            }
        }

        float msk[4];
#pragma unroll
        for (int nj = 0; nj < 4; ++nj) msk[nj] = indks[16 * nj + l15];

#pragma unroll
        for (int reg = 0; reg < 4; ++reg) {
            float sv[4];
            float mx = -INFINITY;
#pragma unroll
            for (int nj = 0; nj < 4; ++nj) {
                sv[nj] = sacc[nj][reg] * 0.125f;
                if (msk[nj] != 0.f) mx = fmaxf(mx, sv[nj]);
            }
            mx = fmaxf(mx, __shfl_xor(mx, 1));
            mx = fmaxf(mx, __shfl_xor(mx, 2));
            mx = fmaxf(mx, __shfl_xor(mx, 4));
            mx = fmaxf(mx, __shfl_xor(mx, 8));
            const float mold = m_i[reg];
            const float mnew = fmaxf(mold, mx);
            const float alpha = (mold == -INFINITY) ? 0.f : __expf(mold - mnew);
            float p[4], rs = 0.f;
#pragma unroll
            for (int nj = 0; nj < 4; ++nj) {
                p[nj] = (msk[nj] != 0.f) ? __expf(sv[nj] - mnew) : 0.f;
                rs += p[nj];
            }
            rs += __shfl_xor(rs, 1);
            rs += __shfl_xor(rs, 2);
            rs += __shfl_xor(rs, 4);
            rs += __shfl_xor(rs, 8);
            l_i[reg] = l_i[reg] * alpha + rs;
            m_i[reg] = mnew;
            const int prow = 16 * w + 4 * quad + reg;
#pragma unroll
            for (int nj = 0; nj < 4; ++nj) {
                oacc[nj][reg] *= alpha;
                Ps[prow * GST + 16 * nj + l15] = (short)f2b(p[nj]);
            }
        }

#pragma unroll
        for (int ks = 0; ks < 2; ++ks) {
            const bf16x8 pa = *(const bf16x8*)&Ps[(16 * w + l15) * GST + 32 * ks + 8 * quad];
#pragma unroll
            for (int nj = 0; nj < 4; ++nj) {
                const bf16x8 vb = *(const bf16x8*)&Vt[(16 * nj + l15) * GST + 32 * ks + 8 * quad];
                oacc[nj] = mfma16(pa, vb, oacc[nj]);
            }
        }
    }

    float inv[4];
#pragma unroll
    for (int reg = 0; reg < 4; ++reg)
        inv[reg] = (l_i[reg] > 0.f) ? 1.f / l_i[reg] : 0.f;
#pragma unroll
    for (int nj = 0; nj < 4; ++nj)
#pragma unroll
        for (int reg = 0; reg < 4; ++reg) {
            const int row = q0 + 16 * w + 4 * quad + reg;
            AO[(size_t)(b * 2048 + row) * 1024 + h * 64 + 16 * nj + l15] =
                f2b(oacc[nj][reg] * inv[reg]);
        }
}

// ---------------------------------------------------------------------------
extern "C" void kernel_launch(void* const* d_in, const int* in_sizes, int n_in,
                              void* d_out, int out_size, void* d_ws, size_t ws_size,
                              hipStream_t stream) {
    const float* q  = (const float*)d_in[0];
    const float* k  = (const float*)d_in[1];
    const float* v  = (const float*)d_in[2];
    const float* iq = (const float*)d_in[3];
    const float* ik = (const float*)d_in[4];
    const float* iv = (const float*)d_in[5];
    const float* Wq = (const float*)d_in[6];
    const float* Wk = (const float*)d_in[7];
    const float* Wv = (const float*)d_in[8];
    const float* Wo = (const float*)d_in[9];
    float* out = (float*)d_out;
    unsigned short* ws = (unsigned short*)d_ws;

    // ws layout (shorts), total 32M shorts = 64 MB:
    const size_t M1 = 1048576;
    unsigned short* qb  = ws;              // 4M
    unsigned short* kb  = ws + 4  * M1;    // 4M
    unsigned short* vb  = ws + 8  * M1;    // 4M
    unsigned short* Wqt = ws + 12 * M1;    // 1M
    unsigned short* Wkt = ws + 13 * M1;
    unsigned short* Wvt = ws + 14 * M1;
    unsigned short* Wot = ws + 15 * M1;
    unsigned short* Qw  = ws + 16 * M1;    // 4M  [B,H,S,HD]
    unsigned short* Kw  = ws + 20 * M1;
    unsigned short* Vw  = ws + 24 * M1;
    unsigned short* AO  = ws + 28 * M1;    // 4M  [4096,1024]

    cvt_bf16<<<dim3(4096), dim3(256), 0, stream>>>(q, qb);
    cvt_bf16<<<dim3(4096), dim3(256), 0, stream>>>(k, kb);
    cvt_bf16<<<dim3(4096), dim3(256), 0, stream>>>(v, vb);
    cvt_tr<<<dim3(16, 16, 4), dim3(256), 0, stream>>>(Wq, Wk, Wv, Wo, Wqt, Wkt, Wvt, Wot);

    const dim3 gg(8, 32);  // N/128, M/128
    gemm128<1><<<gg, dim3(256), 0, stream>>>(qb, Wqt, Qw, iq);
    gemm128<1><<<gg, dim3(256), 0, stream>>>(kb, Wkt, Kw, ik);
    gemm128<1><<<gg, dim3(256), 0, stream>>>(vb, Wvt, Vw, iv);
    attn_mfma<<<dim3(16, 16, 2), dim3(512), 0, stream>>>(Qw, Kw, Vw, ik, AO);
    gemm128<0><<<gg, dim3(256), 0, stream>>>(AO, Wot, out, nullptr);
}

// Round 6
// 343.377 us; speedup vs baseline: 3.4897x; 1.0049x over previous
//
#include <hip/hip_runtime.h>
#include <math.h>

typedef __attribute__((ext_vector_type(8))) short bf16x8;
typedef __attribute__((ext_vector_type(4))) float f32x4;

__device__ __forceinline__ unsigned short f2b(float f) {
    union { float f; unsigned int u; } v; v.f = f;
    unsigned int u = v.u + 0x7FFFu + ((v.u >> 16) & 1u);  // RNE
    return (unsigned short)(u >> 16);
}

// pack two fp32 -> two bf16 in one dword (round-half-up via +0x8000, then v_perm)
__device__ __forceinline__ unsigned int pack2bf(float a, float b) {
    union { float f; unsigned int u; } ua, ub; ua.f = a; ub.f = b;
    return __builtin_amdgcn_perm(ub.u + 0x8000u, ua.u + 0x8000u, 0x07060302u);
}

__device__ __forceinline__ f32x4 mfma16(bf16x8 a, bf16x8 b, f32x4 c) {
    return __builtin_amdgcn_mfma_f32_16x16x32_bf16(a, b, c, 0, 0, 0);
}

// async global->LDS, 16B/lane; LDS dest = wave-uniform base + lane*16
__device__ __forceinline__ void async_ld16(void* l, const void* g) {
    __builtin_amdgcn_global_load_lds(
        (__attribute__((address_space(1))) void*)g,
        (__attribute__((address_space(3))) void*)l, 16, 0, 0);
}

// ---------------------------------------------------------------------------
// fp32 -> bf16 convert, z selects q/k/v
// ---------------------------------------------------------------------------
__global__ __launch_bounds__(256) void cvt3(
    const float* __restrict__ q, const float* __restrict__ k,
    const float* __restrict__ v, unsigned short* __restrict__ qo,
    unsigned short* __restrict__ ko, unsigned short* __restrict__ vo)
{
    const int z = blockIdx.z;
    const float* in = (z == 0) ? q : (z == 1) ? k : v;
    unsigned short* out = (z == 0) ? qo : (z == 1) ? ko : vo;
    const int i = (blockIdx.x * 256 + threadIdx.x) * 4;
    const float4 x = *(const float4*)(in + i);
    ushort4 o; o.x = f2b(x.x); o.y = f2b(x.y); o.z = f2b(x.z); o.w = f2b(x.w);
    *(ushort4*)(out + i) = o;
}

// ---------------------------------------------------------------------------
// Convert + transpose 1024x1024 W [K][N] -> bf16 Wt [N][K]; z selects which W.
// ---------------------------------------------------------------------------
__global__ __launch_bounds__(256) void cvt_tr(
    const float* __restrict__ W0, const float* __restrict__ W1,
    const float* __restrict__ W2, const float* __restrict__ W3,
    unsigned short* __restrict__ T0, unsigned short* __restrict__ T1,
    unsigned short* __restrict__ T2, unsigned short* __restrict__ T3)
{
    const int z = blockIdx.z;
    const float* W = (z == 0) ? W0 : (z == 1) ? W1 : (z == 2) ? W2 : W3;
    unsigned short* T = (z == 0) ? T0 : (z == 1) ? T1 : (z == 2) ? T2 : T3;
    __shared__ short Ls[64 * 65];
    const int t = threadIdx.x;
    const int k0 = blockIdx.x * 64, n0 = blockIdx.y * 64;
#pragma unroll
    for (int ii = 0; ii < 4; ++ii) {
        const int kl = (t >> 4) + 16 * ii, nl = (t & 15) * 4;
        const float4 v = *(const float4*)&W[(size_t)(k0 + kl) * 1024 + n0 + nl];
        Ls[kl * 65 + nl + 0] = (short)f2b(v.x);
        Ls[kl * 65 + nl + 1] = (short)f2b(v.y);
        Ls[kl * 65 + nl + 2] = (short)f2b(v.z);
        Ls[kl * 65 + nl + 3] = (short)f2b(v.w);
    }
    __syncthreads();
#pragma unroll
    for (int ii = 0; ii < 4; ++ii) {
        const int nl = (t >> 4) + 16 * ii, kl = (t & 15) * 4;
        ushort4 o;
        o.x = (unsigned short)Ls[(kl + 0) * 65 + nl];
        o.y = (unsigned short)Ls[(kl + 1) * 65 + nl];
        o.z = (unsigned short)Ls[(kl + 2) * 65 + nl];
        o.w = (unsigned short)Ls[(kl + 3) * 65 + nl];
        *(ushort4*)&T[(size_t)(n0 + nl) * 1024 + k0 + kl] = o;
    }
}

// ---------------------------------------------------------------------------
// Projection GEMMs, z-batched: C_z = mask_z-scatter(A_z[4096x1024] @ Wt_z^T).
// BM=128, BN=64, BK=32. 256 thr = 4 waves 2x2 (wave tile 64x32).
// z==0 (Q) folds the 1/sqrt(64) attention scale into the mask.
// ---------------------------------------------------------------------------
__global__ __launch_bounds__(256) void gemm_proj3(
    const unsigned short* __restrict__ qb, const unsigned short* __restrict__ kb,
    const unsigned short* __restrict__ vb,
    const unsigned short* __restrict__ Wqt, const unsigned short* __restrict__ Wkt,
    const unsigned short* __restrict__ Wvt,
    unsigned short* __restrict__ Qw, unsigned short* __restrict__ Kw,
    unsigned short* __restrict__ Vw,
    const float* __restrict__ iq, const float* __restrict__ ik,
    const float* __restrict__ iv)
{
    const int z = blockIdx.z;
    const unsigned short* A  = (z == 0) ? qb  : (z == 1) ? kb  : vb;
    const unsigned short* Bt = (z == 0) ? Wqt : (z == 1) ? Wkt : Wvt;
    unsigned short* Cw       = (z == 0) ? Qw  : (z == 1) ? Kw  : Vw;
    const float* msk         = (z == 0) ? iq  : (z == 1) ? ik  : iv;
    const float scale = (z == 0) ? 0.125f : 1.0f;

    __shared__ __align__(16) short As[128 * 32];
    __shared__ __align__(16) short Bs[64 * 32];
    __shared__ float maskL[128];
    const int t = threadIdx.x;
    const int w = t >> 6, lane = t & 63, l15 = lane & 15, quad = lane >> 4;
    const int wr = w >> 1, wc = w & 1;
    const int n0 = blockIdx.x * 64, m0 = blockIdx.y * 128;
    if (t < 128) maskL[t] = msk[m0 + t] * scale;

    const int srow = lane >> 2, soff = (lane & 3) * 8;

    f32x4 zero4 = {0.f, 0.f, 0.f, 0.f};
    f32x4 acc[4][2];
#pragma unroll
    for (int i = 0; i < 4; ++i) { acc[i][0] = zero4; acc[i][1] = zero4; }

    for (int k0 = 0; k0 < 1024; k0 += 32) {
        __syncthreads();
#pragma unroll
        for (int i = 0; i < 2; ++i) {
            const int r = 16 * (2 * w + i);
            async_ld16(As + r * 32, A + (size_t)(m0 + r + srow) * 1024 + k0 + soff);
        }
        async_ld16(Bs + (16 * w) * 32, Bt + (size_t)(n0 + 16 * w + srow) * 1024 + k0 + soff);
        __syncthreads();
        bf16x8 af[4], bfr[2];
#pragma unroll
        for (int i = 0; i < 4; ++i)
            af[i] = *(const bf16x8*)&As[(64 * wr + 16 * i + l15) * 32 + 8 * quad];
#pragma unroll
        for (int j = 0; j < 2; ++j)
            bfr[j] = *(const bf16x8*)&Bs[(32 * wc + 16 * j + l15) * 32 + 8 * quad];
#pragma unroll
        for (int i = 0; i < 4; ++i)
#pragma unroll
            for (int j = 0; j < 2; ++j)
                acc[i][j] = mfma16(af[i], bfr[j], acc[i][j]);
    }

    const int h = blockIdx.x;  // BN=64 == one head
#pragma unroll
    for (int i = 0; i < 4; ++i)
#pragma unroll
        for (int j = 0; j < 2; ++j)
#pragma unroll
            for (int reg = 0; reg < 4; ++reg) {
                const int mloc = 64 * wr + 16 * i + 4 * quad + reg;
                const int m = m0 + mloc;
                const int bb = m >> 11, s = m & 2047;
                const int hd = 32 * wc + 16 * j + l15;
                Cw[((size_t)(bb * 16 + h) * 2048 + s) * 64 + hd] =
                    f2b(acc[i][j][reg] * maskL[mloc]);
            }
}

// ---------------------------------------------------------------------------
// Output GEMM: out[4096x1024]f32 = AO[4096x1024]bf16 @ Wot^T. BM=128 BN=64.
// ---------------------------------------------------------------------------
__global__ __launch_bounds__(256) void gemm_out(
    const unsigned short* __restrict__ A, const unsigned short* __restrict__ Bt,
    float* __restrict__ C)
{
    __shared__ __align__(16) short As[128 * 32];
    __shared__ __align__(16) short Bs[64 * 32];
    const int t = threadIdx.x;
    const int w = t >> 6, lane = t & 63, l15 = lane & 15, quad = lane >> 4;
    const int wr = w >> 1, wc = w & 1;
    const int n0 = blockIdx.x * 64, m0 = blockIdx.y * 128;
    const int srow = lane >> 2, soff = (lane & 3) * 8;

    f32x4 zero4 = {0.f, 0.f, 0.f, 0.f};
    f32x4 acc[4][2];
#pragma unroll
    for (int i = 0; i < 4; ++i) { acc[i][0] = zero4; acc[i][1] = zero4; }

    for (int k0 = 0; k0 < 1024; k0 += 32) {
        __syncthreads();
#pragma unroll
        for (int i = 0; i < 2; ++i) {
            const int r = 16 * (2 * w + i);
            async_ld16(As + r * 32, A + (size_t)(m0 + r + srow) * 1024 + k0 + soff);
        }
        async_ld16(Bs + (16 * w) * 32, Bt + (size_t)(n0 + 16 * w + srow) * 1024 + k0 + soff);
        __syncthreads();
        bf16x8 af[4], bfr[2];
#pragma unroll
        for (int i = 0; i < 4; ++i)
            af[i] = *(const bf16x8*)&As[(64 * wr + 16 * i + l15) * 32 + 8 * quad];
#pragma unroll
        for (int j = 0; j < 2; ++j)
            bfr[j] = *(const bf16x8*)&Bs[(32 * wc + 16 * j + l15) * 32 + 8 * quad];
#pragma unroll
        for (int i = 0; i < 4; ++i)
#pragma unroll
            for (int j = 0; j < 2; ++j)
                acc[i][j] = mfma16(af[i], bfr[j], acc[i][j]);
    }
#pragma unroll
    for (int i = 0; i < 4; ++i)
#pragma unroll
        for (int j = 0; j < 2; ++j)
#pragma unroll
            for (int reg = 0; reg < 4; ++reg) {
                const int m = m0 + 64 * wr + 16 * i + 4 * quad + reg;
                const int n = n0 + 32 * wc + 16 * j + l15;
                C[(size_t)m * 1024 + n] = acc[i][j][reg];
            }
}

#define GST 72  // attn LDS row stride (shorts): 144B, b128-aligned

// ---------------------------------------------------------------------------
// MFMA flash attention, S^T formulation.
// S^T = K·Q^T (C col = q) -> per-lane softmax state is for ONE q-row:
// in-lane reduce over 16 keys + xor16/xor32 shuffles. Mask folds in as an
// additive -1e30 bias; mnew clamped >= -1e28 so fully-masked chunks give p=0.
// Q pre-scaled by 1/8 in gemm_proj3. Q-frags live in registers (staged via Ps).
// 512 thr = 8 waves, Q-tile 128, 64-key chunks. l==0 guard -> zero output.
// ---------------------------------------------------------------------------
__global__ __launch_bounds__(512, 8) void attn_mfma(
    const unsigned short* __restrict__ Qw, const unsigned short* __restrict__ Kw,
    const unsigned short* __restrict__ Vw, const float* __restrict__ indk,
    unsigned short* __restrict__ AO)
{
    __shared__ __align__(16) short Ks[64 * GST];
    __shared__ __align__(16) short Vt[64 * GST];   // Vt[dim][key]
    __shared__ __align__(16) short Ps[128 * GST];  // P[q][key]; also Q staging
    __shared__ float biask[64];
    const int t = threadIdx.x;
    const int w = t >> 6, lane = t & 63, l15 = lane & 15, quad = lane >> 4;
    const int q0 = blockIdx.x * 128;
    const int h = blockIdx.y, b = blockIdx.z;
    const size_t base = (size_t)(b * 16 + h) * (2048 * 64);
    const unsigned short* Qb = Qw + base + (size_t)q0 * 64;
    const unsigned short* Kb = Kw + base;
    const unsigned short* Vb = Vw + base;

    // stage Q tile into Ps, pull own wave's A-frags to registers
#pragma unroll
    for (int i = 0; i < 4; ++i) {
        const int idx = t + 512 * i;
        const int r = idx >> 4, dg = (idx & 15) * 4;
        *(ushort4*)&Ps[r * GST + dg] = *(const ushort4*)&Qb[r * 64 + dg];
    }
    __syncthreads();
    bf16x8 qf[2];
    qf[0] = *(const bf16x8*)&Ps[(16 * w + l15) * GST + 8 * quad];
    qf[1] = *(const bf16x8*)&Ps[(16 * w + l15) * GST + 32 + 8 * quad];

    f32x4 zero4 = {0.f, 0.f, 0.f, 0.f};
    f32x4 oacc[4];
    oacc[0] = zero4; oacc[1] = zero4; oacc[2] = zero4; oacc[3] = zero4;
    float m_i = -INFINITY, l_i = 0.f;

    for (int k0 = 0; k0 < 2048; k0 += 64) {
        __syncthreads();  // all waves done reading previous Ks/Vt (and Ps-as-Q)
#pragma unroll
        for (int i = 0; i < 2; ++i) {
            const int idx = t + 512 * i;
            const int r = idx >> 4, dg = (idx & 15) * 4;
            *(ushort4*)&Ks[r * GST + dg] = *(const ushort4*)&Kb[(size_t)(k0 + r) * 64 + dg];
            const int key = idx & 63, dq = idx >> 6;
            const ushort4 vv = *(const ushort4*)&Vb[(size_t)(k0 + key) * 64 + 4 * dq];
            Vt[(4 * dq + 0) * GST + key] = vv.x;
            Vt[(4 * dq + 1) * GST + key] = vv.y;
            Vt[(4 * dq + 2) * GST + key] = vv.z;
            Vt[(4 * dq + 3) * GST + key] = vv.w;
        }
        if (t < 64) biask[t] = (indk[b * 2048 + k0 + t] != 0.f) ? 0.f : -1e30f;
        __syncthreads();

        // S^T tiles: C[key=16nj+4quad+reg][q=16w+l15]
        f32x4 sacc[4];
        sacc[0] = zero4; sacc[1] = zero4; sacc[2] = zero4; sacc[3] = zero4;
#pragma unroll
        for (int ks = 0; ks < 2; ++ks)
#pragma unroll
            for (int nj = 0; nj < 4; ++nj) {
                const bf16x8 kf = *(const bf16x8*)&Ks[(16 * nj + l15) * GST + 32 * ks + 8 * quad];
                sacc[nj] = mfma16(kf, qf[ks], sacc[nj]);
            }

        // add mask bias
#pragma unroll
        for (int nj = 0; nj < 4; ++nj) {
            const float4 bv = *(const float4*)&biask[16 * nj + 4 * quad];
            sacc[nj][0] += bv.x; sacc[nj][1] += bv.y;
            sacc[nj][2] += bv.z; sacc[nj][3] += bv.w;
        }

        // online softmax for q = 16w + l15 (state per lane)
        float mx = -INFINITY;
#pragma unroll
        for (int nj = 0; nj < 4; ++nj)
#pragma unroll
            for (int r = 0; r < 4; ++r) mx = fmaxf(mx, sacc[nj][r]);
        mx = fmaxf(mx, __shfl_xor(mx, 16));
        mx = fmaxf(mx, __shfl_xor(mx, 32));
        const float mnew = fmaxf(fmaxf(m_i, mx), -1e28f);  // clamp: all-masked -> p=0
        const float alpha = __expf(m_i - mnew);            // m_i=-inf -> 0
        float rs = 0.f;
#pragma unroll
        for (int nj = 0; nj < 4; ++nj)
#pragma unroll
            for (int r = 0; r < 4; ++r) {
                const float p = __expf(sacc[nj][r] - mnew);
                sacc[nj][r] = p;
                rs += p;
            }
        rs += __shfl_xor(rs, 16);
        rs += __shfl_xor(rs, 32);
        l_i = l_i * alpha + rs;
        m_i = mnew;

        // store P rows (own wave's q rows only -> no cross-wave hazard)
#pragma unroll
        for (int nj = 0; nj < 4; ++nj) {
            uint2 d;
            d.x = pack2bf(sacc[nj][0], sacc[nj][1]);
            d.y = pack2bf(sacc[nj][2], sacc[nj][3]);
            *(uint2*)&Ps[(16 * w + l15) * GST + 16 * nj + 4 * quad] = d;
        }

        // rescale O (row-layout q = 16w + 4quad + reg; alpha lives at col-lane)
        float ar[4];
#pragma unroll
        for (int r = 0; r < 4; ++r) ar[r] = __shfl(alpha, 4 * quad + r);
#pragma unroll
        for (int nj = 0; nj < 4; ++nj)
#pragma unroll
            for (int r = 0; r < 4; ++r) oacc[nj][r] *= ar[r];

        // O += P V (same-wave Ps rows; compiler inserts lgkmcnt waits)
#pragma unroll
        for (int ks = 0; ks < 2; ++ks) {
            const bf16x8 pa = *(const bf16x8*)&Ps[(16 * w + l15) * GST + 32 * ks + 8 * quad];
#pragma unroll
            for (int nj = 0; nj < 4; ++nj) {
                const bf16x8 vbf = *(const bf16x8*)&Vt[(16 * nj + l15) * GST + 32 * ks + 8 * quad];
                oacc[nj] = mfma16(pa, vbf, oacc[nj]);
            }
        }
    }

    const float inv = (l_i > 0.f) ? 1.f / l_i : 0.f;  // zero-row guard
    float invr[4];
#pragma unroll
    for (int r = 0; r < 4; ++r) invr[r] = __shfl(inv, 4 * quad + r);
#pragma unroll
    for (int nj = 0; nj < 4; ++nj)
#pragma unroll
        for (int r = 0; r < 4; ++r) {
            const int row = q0 + 16 * w + 4 * quad + r;
            AO[(size_t)(b * 2048 + row) * 1024 + h * 64 + 16 * nj + l15] =
                f2b(oacc[nj][r] * invr[r]);
        }
}

// ---------------------------------------------------------------------------
extern "C" void kernel_launch(void* const* d_in, const int* in_sizes, int n_in,
                              void* d_out, int out_size, void* d_ws, size_t ws_size,
                              hipStream_t stream) {
    const float* q  = (const float*)d_in[0];
    const float* k  = (const float*)d_in[1];
    const float* v  = (const float*)d_in[2];
    const float* iq = (const float*)d_in[3];
    const float* ik = (const float*)d_in[4];
    const float* iv = (const float*)d_in[5];
    const float* Wq = (const float*)d_in[6];
    const float* Wk = (const float*)d_in[7];
    const float* Wv = (const float*)d_in[8];
    const float* Wo = (const float*)d_in[9];
    float* out = (float*)d_out;
    unsigned short* ws = (unsigned short*)d_ws;

    const size_t M1 = 1048576;
    unsigned short* qb  = ws;
    unsigned short* kb  = ws + 4  * M1;
    unsigned short* vb  = ws + 8  * M1;
    unsigned short* Wqt = ws + 12 * M1;
    unsigned short* Wkt = ws + 13 * M1;
    unsigned short* Wvt = ws + 14 * M1;
    unsigned short* Wot = ws + 15 * M1;
    unsigned short* Qw  = ws + 16 * M1;
    unsigned short* Kw  = ws + 20 * M1;
    unsigned short* Vw  = ws + 24 * M1;
    unsigned short* AO  = ws + 28 * M1;

    cvt3<<<dim3(4096, 1, 3), dim3(256), 0, stream>>>(q, k, v, qb, kb, vb);
    cvt_tr<<<dim3(16, 16, 4), dim3(256), 0, stream>>>(Wq, Wk, Wv, Wo, Wqt, Wkt, Wvt, Wot);
    gemm_proj3<<<dim3(16, 32, 3), dim3(256), 0, stream>>>(
        qb, kb, vb, Wqt, Wkt, Wvt, Qw, Kw, Vw, iq, ik, iv);
    attn_mfma<<<dim3(16, 16, 2), dim3(512), 0, stream>>>(Qw, Kw, Vw, ik, AO);
    gemm_out<<<dim3(16, 32), dim3(256), 0, stream>>>(AO, Wot, out);
}

// Round 7
// 253.600 us; speedup vs baseline: 4.7251x; 1.3540x over previous
//
#include <hip/hip_runtime.h>
#include <math.h>

typedef __attribute__((ext_vector_type(8))) short bf16x8;
typedef __attribute__((ext_vector_type(4))) float f32x4;

__device__ __forceinline__ unsigned short f2b(float f) {
    union { float f; unsigned int u; } v; v.f = f;
    unsigned int u = v.u + 0x7FFFu + ((v.u >> 16) & 1u);  // RNE
    return (unsigned short)(u >> 16);
}

// pack two fp32 -> two bf16 in one dword
__device__ __forceinline__ unsigned int pack2bf(float a, float b) {
    union { float f; unsigned int u; } ua, ub; ua.f = a; ub.f = b;
    return __builtin_amdgcn_perm(ub.u + 0x8000u, ua.u + 0x8000u, 0x07060302u);
}

__device__ __forceinline__ f32x4 mfma16(bf16x8 a, bf16x8 b, f32x4 c) {
    return __builtin_amdgcn_mfma_f32_16x16x32_bf16(a, b, c, 0, 0, 0);
}

__device__ __forceinline__ void async_ld16(void* l, const void* g) {
    __builtin_amdgcn_global_load_lds(
        (__attribute__((address_space(1))) void*)g,
        (__attribute__((address_space(3))) void*)l, 16, 0, 0);
}

// ---------------------------------------------------------------------------
// fp32 -> bf16 convert, z selects q/k/v
// ---------------------------------------------------------------------------
__global__ __launch_bounds__(256) void cvt3(
    const float* __restrict__ q, const float* __restrict__ k,
    const float* __restrict__ v, unsigned short* __restrict__ qo,
    unsigned short* __restrict__ ko, unsigned short* __restrict__ vo)
{
    const int z = blockIdx.z;
    const float* in = (z == 0) ? q : (z == 1) ? k : v;
    unsigned short* out = (z == 0) ? qo : (z == 1) ? ko : vo;
    const int i = (blockIdx.x * 256 + threadIdx.x) * 4;
    const float4 x = *(const float4*)(in + i);
    ushort4 o; o.x = f2b(x.x); o.y = f2b(x.y); o.z = f2b(x.z); o.w = f2b(x.w);
    *(ushort4*)(out + i) = o;
}

// ---------------------------------------------------------------------------
// Convert + transpose 1024x1024 W [K][N] -> bf16 Wt [N][K]; z selects which W.
// ---------------------------------------------------------------------------
__global__ __launch_bounds__(256) void cvt_tr(
    const float* __restrict__ W0, const float* __restrict__ W1,
    const float* __restrict__ W2, const float* __restrict__ W3,
    unsigned short* __restrict__ T0, unsigned short* __restrict__ T1,
    unsigned short* __restrict__ T2, unsigned short* __restrict__ T3)
{
    const int z = blockIdx.z;
    const float* W = (z == 0) ? W0 : (z == 1) ? W1 : (z == 2) ? W2 : W3;
    unsigned short* T = (z == 0) ? T0 : (z == 1) ? T1 : (z == 2) ? T2 : T3;
    __shared__ short Ls[64 * 65];
    const int t = threadIdx.x;
    const int k0 = blockIdx.x * 64, n0 = blockIdx.y * 64;
#pragma unroll
    for (int ii = 0; ii < 4; ++ii) {
        const int kl = (t >> 4) + 16 * ii, nl = (t & 15) * 4;
        const float4 v = *(const float4*)&W[(size_t)(k0 + kl) * 1024 + n0 + nl];
        Ls[kl * 65 + nl + 0] = (short)f2b(v.x);
        Ls[kl * 65 + nl + 1] = (short)f2b(v.y);
        Ls[kl * 65 + nl + 2] = (short)f2b(v.z);
        Ls[kl * 65 + nl + 3] = (short)f2b(v.w);
    }
    __syncthreads();
#pragma unroll
    for (int ii = 0; ii < 4; ++ii) {
        const int nl = (t >> 4) + 16 * ii, kl = (t & 15) * 4;
        ushort4 o;
        o.x = (unsigned short)Ls[(kl + 0) * 65 + nl];
        o.y = (unsigned short)Ls[(kl + 1) * 65 + nl];
        o.z = (unsigned short)Ls[(kl + 2) * 65 + nl];
        o.w = (unsigned short)Ls[(kl + 3) * 65 + nl];
        *(ushort4*)&T[(size_t)(n0 + nl) * 1024 + k0 + kl] = o;
    }
}

// ---------------------------------------------------------------------------
// Projection GEMMs, z-batched, m97 shape: BM=BN=128, BK=32, 4 waves 2x2,
// wave tile 64x64, 16 mfma / 8 b128 frag reads per wave-iter.
// Epilogue: mask (z==0 also folds 1/8 attn scale) + scatter bf16 [B,H,S,HD].
// ---------------------------------------------------------------------------
__global__ __launch_bounds__(256) void gemm_proj3(
    const unsigned short* __restrict__ qb, const unsigned short* __restrict__ kb,
    const unsigned short* __restrict__ vb,
    const unsigned short* __restrict__ Wqt, const unsigned short* __restrict__ Wkt,
    const unsigned short* __restrict__ Wvt,
    unsigned short* __restrict__ Qw, unsigned short* __restrict__ Kw,
    unsigned short* __restrict__ Vw,
    const float* __restrict__ iq, const float* __restrict__ ik,
    const float* __restrict__ iv)
{
    const int z = blockIdx.z;
    const unsigned short* A  = (z == 0) ? qb  : (z == 1) ? kb  : vb;
    const unsigned short* Bt = (z == 0) ? Wqt : (z == 1) ? Wkt : Wvt;
    unsigned short* Cw       = (z == 0) ? Qw  : (z == 1) ? Kw  : Vw;
    const float* msk         = (z == 0) ? iq  : (z == 1) ? ik  : iv;
    const float scale = (z == 0) ? 0.125f : 1.0f;

    __shared__ __align__(16) short As[128 * 32];
    __shared__ __align__(16) short Bs[128 * 32];
    __shared__ float maskL[128];
    const int t = threadIdx.x;
    const int w = t >> 6, lane = t & 63, l15 = lane & 15, quad = lane >> 4;
    const int wr = w >> 1, wc = w & 1;
    const int n0 = blockIdx.x * 128, m0 = blockIdx.y * 128;
    if (t < 128) maskL[t] = msk[m0 + t] * scale;

    const int srow = lane >> 2, soff = (lane & 3) * 8;

    f32x4 zero4 = {0.f, 0.f, 0.f, 0.f};
    f32x4 acc[4][4];
#pragma unroll
    for (int i = 0; i < 4; ++i)
#pragma unroll
        for (int j = 0; j < 4; ++j) acc[i][j] = zero4;

    for (int k0 = 0; k0 < 1024; k0 += 32) {
        __syncthreads();
#pragma unroll
        for (int i = 0; i < 2; ++i) {
            const int r = 16 * (2 * w + i);
            async_ld16(As + r * 32, A + (size_t)(m0 + r + srow) * 1024 + k0 + soff);
            async_ld16(Bs + r * 32, Bt + (size_t)(n0 + r + srow) * 1024 + k0 + soff);
        }
        __syncthreads();
        bf16x8 af[4], bfr[4];
#pragma unroll
        for (int i = 0; i < 4; ++i)
            af[i] = *(const bf16x8*)&As[(64 * wr + 16 * i + l15) * 32 + 8 * quad];
#pragma unroll
        for (int j = 0; j < 4; ++j)
            bfr[j] = *(const bf16x8*)&Bs[(64 * wc + 16 * j + l15) * 32 + 8 * quad];
#pragma unroll
        for (int i = 0; i < 4; ++i)
#pragma unroll
            for (int j = 0; j < 4; ++j)
                acc[i][j] = mfma16(af[i], bfr[j], acc[i][j]);
    }

    const int h = 2 * blockIdx.x + wc;  // 64-col wave tile == one head
#pragma unroll
    for (int i = 0; i < 4; ++i)
#pragma unroll
        for (int j = 0; j < 4; ++j)
#pragma unroll
            for (int reg = 0; reg < 4; ++reg) {
                const int mloc = 64 * wr + 16 * i + 4 * quad + reg;
                const int m = m0 + mloc;
                const int bb = m >> 11, s = m & 2047;
                const int hd = 16 * j + l15;
                Cw[((size_t)(bb * 16 + h) * 2048 + s) * 64 + hd] =
                    f2b(acc[i][j][reg] * maskL[mloc]);
            }
}

// ---------------------------------------------------------------------------
// Output GEMM: out[4096x1024]f32 = AO bf16 @ Wot^T. BM=128 BN=64 (512 blocks).
// ---------------------------------------------------------------------------
__global__ __launch_bounds__(256) void gemm_out(
    const unsigned short* __restrict__ A, const unsigned short* __restrict__ Bt,
    float* __restrict__ C)
{
    __shared__ __align__(16) short As[128 * 32];
    __shared__ __align__(16) short Bs[64 * 32];
    const int t = threadIdx.x;
    const int w = t >> 6, lane = t & 63, l15 = lane & 15, quad = lane >> 4;
    const int wr = w >> 1, wc = w & 1;
    const int n0 = blockIdx.x * 64, m0 = blockIdx.y * 128;
    const int srow = lane >> 2, soff = (lane & 3) * 8;

    f32x4 zero4 = {0.f, 0.f, 0.f, 0.f};
    f32x4 acc[4][2];
#pragma unroll
    for (int i = 0; i < 4; ++i) { acc[i][0] = zero4; acc[i][1] = zero4; }

    for (int k0 = 0; k0 < 1024; k0 += 32) {
        __syncthreads();
#pragma unroll
        for (int i = 0; i < 2; ++i) {
            const int r = 16 * (2 * w + i);
            async_ld16(As + r * 32, A + (size_t)(m0 + r + srow) * 1024 + k0 + soff);
        }
        async_ld16(Bs + (16 * w) * 32, Bt + (size_t)(n0 + 16 * w + srow) * 1024 + k0 + soff);
        __syncthreads();
        bf16x8 af[4], bfr[2];
#pragma unroll
        for (int i = 0; i < 4; ++i)
            af[i] = *(const bf16x8*)&As[(64 * wr + 16 * i + l15) * 32 + 8 * quad];
#pragma unroll
        for (int j = 0; j < 2; ++j)
            bfr[j] = *(const bf16x8*)&Bs[(32 * wc + 16 * j + l15) * 32 + 8 * quad];
#pragma unroll
        for (int i = 0; i < 4; ++i)
#pragma unroll
            for (int j = 0; j < 2; ++j)
                acc[i][j] = mfma16(af[i], bfr[j], acc[i][j]);
    }
#pragma unroll
    for (int i = 0; i < 4; ++i)
#pragma unroll
        for (int j = 0; j < 2; ++j)
#pragma unroll
            for (int reg = 0; reg < 4; ++reg) {
                const int m = m0 + 64 * wr + 16 * i + 4 * quad + reg;
                const int n = n0 + 32 * wc + 16 * j + l15;
                C[(size_t)m * 1024 + n] = acc[i][j][reg];
            }
}

#define GST 72  // attn LDS row stride (shorts): 144B, b128-aligned

// ---------------------------------------------------------------------------
// MFMA flash attention, S^T formulation + software-pipelined K/V staging.
// Double-buffered Ks/Vt/bias; chunk i+1 loads issued right after the barrier
// (vmcnt consumed a full compute-phase later). ONE barrier per chunk.
// ---------------------------------------------------------------------------
__global__ __launch_bounds__(512, 4) void attn_mfma(
    const unsigned short* __restrict__ Qw, const unsigned short* __restrict__ Kw,
    const unsigned short* __restrict__ Vw, const float* __restrict__ indk,
    unsigned short* __restrict__ AO)
{
    __shared__ __align__(16) short Ks[2][64 * GST];
    __shared__ __align__(16) short Vt[2][64 * GST];   // Vt[dim][key]
    __shared__ __align__(16) short Ps[128 * GST];     // P[q][key]; also Q staging
    __shared__ float biask[2][64];
    const int t = threadIdx.x;
    const int w = t >> 6, lane = t & 63, l15 = lane & 15, quad = lane >> 4;
    const int q0 = blockIdx.x * 128;
    const int h = blockIdx.y, b = blockIdx.z;
    const size_t base = (size_t)(b * 16 + h) * (2048 * 64);
    const unsigned short* Qb = Qw + base + (size_t)q0 * 64;
    const unsigned short* Kb = Kw + base;
    const unsigned short* Vb = Vw + base;

    // stage Q tile into Ps, pull own wave's A-frags to registers
#pragma unroll
    for (int i = 0; i < 4; ++i) {
        const int idx = t + 512 * i;
        const int r = idx >> 4, dg = (idx & 15) * 4;
        *(ushort4*)&Ps[r * GST + dg] = *(const ushort4*)&Qb[r * 64 + dg];
    }
    // preload chunk 0 into regs (overlaps the Q staging)
    ushort4 kreg[2], vreg[2];
    float breg = 0.f;
#pragma unroll
    for (int u = 0; u < 2; ++u) {
        const int idx = t + 512 * u;
        kreg[u] = *(const ushort4*)&Kb[(size_t)(idx >> 4) * 64 + (idx & 15) * 4];
        vreg[u] = *(const ushort4*)&Vb[(size_t)(idx & 63) * 64 + (idx >> 6) * 4];
    }
    if (t < 64) breg = indk[b * 2048 + t];
    __syncthreads();
    bf16x8 qf[2];
    qf[0] = *(const bf16x8*)&Ps[(16 * w + l15) * GST + 8 * quad];
    qf[1] = *(const bf16x8*)&Ps[(16 * w + l15) * GST + 32 + 8 * quad];

    f32x4 zero4 = {0.f, 0.f, 0.f, 0.f};
    f32x4 oacc[4];
    oacc[0] = zero4; oacc[1] = zero4; oacc[2] = zero4; oacc[3] = zero4;
    float m_i = -INFINITY, l_i = 0.f;

    for (int c = 0; c < 32; ++c) {
        const int cur = c & 1;
        // 1. write staged regs (chunk c) -> LDS buf cur
#pragma unroll
        for (int u = 0; u < 2; ++u) {
            const int idx = t + 512 * u;
            const int r = idx >> 4, dg = (idx & 15) * 4;
            *(ushort4*)&Ks[cur][r * GST + dg] = kreg[u];
            const int key = idx & 63, dq = idx >> 6;
            Vt[cur][(4 * dq + 0) * GST + key] = vreg[u].x;
            Vt[cur][(4 * dq + 1) * GST + key] = vreg[u].y;
            Vt[cur][(4 * dq + 2) * GST + key] = vreg[u].z;
            Vt[cur][(4 * dq + 3) * GST + key] = vreg[u].w;
        }
        if (t < 64) biask[cur][t] = (breg != 0.f) ? 0.f : -1e30f;
        __syncthreads();  // the ONLY barrier per chunk
        // 2. issue chunk c+1 loads (clamped; consumed next iter after compute)
        {
            const int kn = (c < 31 ? c + 1 : 31) * 64;
#pragma unroll
            for (int u = 0; u < 2; ++u) {
                const int idx = t + 512 * u;
                kreg[u] = *(const ushort4*)&Kb[(size_t)(kn + (idx >> 4)) * 64 + (idx & 15) * 4];
                vreg[u] = *(const ushort4*)&Vb[(size_t)(kn + (idx & 63)) * 64 + (idx >> 6) * 4];
            }
            if (t < 64) breg = indk[b * 2048 + kn + t];
        }
        // 3. compute chunk c from buf cur
        const short* KsC = Ks[cur];
        const short* VtC = Vt[cur];

        f32x4 sacc[4];
        sacc[0] = zero4; sacc[1] = zero4; sacc[2] = zero4; sacc[3] = zero4;
#pragma unroll
        for (int ks = 0; ks < 2; ++ks)
#pragma unroll
            for (int nj = 0; nj < 4; ++nj) {
                const bf16x8 kf = *(const bf16x8*)&KsC[(16 * nj + l15) * GST + 32 * ks + 8 * quad];
                sacc[nj] = mfma16(kf, qf[ks], sacc[nj]);
            }

#pragma unroll
        for (int nj = 0; nj < 4; ++nj) {
            const float4 bv = *(const float4*)&biask[cur][16 * nj + 4 * quad];
            sacc[nj][0] += bv.x; sacc[nj][1] += bv.y;
            sacc[nj][2] += bv.z; sacc[nj][3] += bv.w;
        }

        float mx = -INFINITY;
#pragma unroll
        for (int nj = 0; nj < 4; ++nj)
#pragma unroll
            for (int r = 0; r < 4; ++r) mx = fmaxf(mx, sacc[nj][r]);
        mx = fmaxf(mx, __shfl_xor(mx, 16));
        mx = fmaxf(mx, __shfl_xor(mx, 32));
        const float mnew = fmaxf(fmaxf(m_i, mx), -1e28f);  // all-masked -> p=0
        const float alpha = __expf(m_i - mnew);            // m_i=-inf -> 0
        float rs = 0.f;
#pragma unroll
        for (int nj = 0; nj < 4; ++nj)
#pragma unroll
            for (int r = 0; r < 4; ++r) {
                const float p = __expf(sacc[nj][r] - mnew);
                sacc[nj][r] = p;
                rs += p;
            }
        rs += __shfl_xor(rs, 16);
        rs += __shfl_xor(rs, 32);
        l_i = l_i * alpha + rs;
        m_i = mnew;

        // P store (own wave's rows only -> same-wave, no barrier)
#pragma unroll
        for (int nj = 0; nj < 4; ++nj) {
            uint2 d;
            d.x = pack2bf(sacc[nj][0], sacc[nj][1]);
            d.y = pack2bf(sacc[nj][2], sacc[nj][3]);
            *(uint2*)&Ps[(16 * w + l15) * GST + 16 * nj + 4 * quad] = d;
        }

        float ar[4];
#pragma unroll
        for (int r = 0; r < 4; ++r) ar[r] = __shfl(alpha, 4 * quad + r);
#pragma unroll
        for (int nj = 0; nj < 4; ++nj)
#pragma unroll
            for (int r = 0; r < 4; ++r) oacc[nj][r] *= ar[r];

#pragma unroll
        for (int ks = 0; ks < 2; ++ks) {
            const bf16x8 pa = *(const bf16x8*)&Ps[(16 * w + l15) * GST + 32 * ks + 8 * quad];
#pragma unroll
            for (int nj = 0; nj < 4; ++nj) {
                const bf16x8 vbf = *(const bf16x8*)&VtC[(16 * nj + l15) * GST + 32 * ks + 8 * quad];
                oacc[nj] = mfma16(pa, vbf, oacc[nj]);
            }
        }
    }

    const float inv = (l_i > 0.f) ? 1.f / l_i : 0.f;  // zero-row guard
    float invr[4];
#pragma unroll
    for (int r = 0; r < 4; ++r) invr[r] = __shfl(inv, 4 * quad + r);
#pragma unroll
    for (int nj = 0; nj < 4; ++nj)
#pragma unroll
        for (int r = 0; r < 4; ++r) {
            const int row = q0 + 16 * w + 4 * quad + r;
            AO[(size_t)(b * 2048 + row) * 1024 + h * 64 + 16 * nj + l15] =
                f2b(oacc[nj][r] * invr[r]);
        }
}

// ---------------------------------------------------------------------------
extern "C" void kernel_launch(void* const* d_in, const int* in_sizes, int n_in,
                              void* d_out, int out_size, void* d_ws, size_t ws_size,
                              hipStream_t stream) {
    const float* q  = (const float*)d_in[0];
    const float* k  = (const float*)d_in[1];
    const float* v  = (const float*)d_in[2];
    const float* iq = (const float*)d_in[3];
    const float* ik = (const float*)d_in[4];
    const float* iv = (const float*)d_in[5];
    const float* Wq = (const float*)d_in[6];
    const float* Wk = (const float*)d_in[7];
    const float* Wv = (const float*)d_in[8];
    const float* Wo = (const float*)d_in[9];
    float* out = (float*)d_out;
    unsigned short* ws = (unsigned short*)d_ws;

    const size_t M1 = 1048576;
    unsigned short* qb  = ws;
    unsigned short* kb  = ws + 4  * M1;
    unsigned short* vb  = ws + 8  * M1;
    unsigned short* Wqt = ws + 12 * M1;
    unsigned short* Wkt = ws + 13 * M1;
    unsigned short* Wvt = ws + 14 * M1;
    unsigned short* Wot = ws + 15 * M1;
    unsigned short* Qw  = ws + 16 * M1;
    unsigned short* Kw  = ws + 20 * M1;
    unsigned short* Vw  = ws + 24 * M1;
    unsigned short* AO  = ws + 28 * M1;

    cvt3<<<dim3(4096, 1, 3), dim3(256), 0, stream>>>(q, k, v, qb, kb, vb);
    cvt_tr<<<dim3(16, 16, 4), dim3(256), 0, stream>>>(Wq, Wk, Wv, Wo, Wqt, Wkt, Wvt, Wot);
    gemm_proj3<<<dim3(8, 32, 3), dim3(256), 0, stream>>>(
        qb, kb, vb, Wqt, Wkt, Wvt, Qw, Kw, Vw, iq, ik, iv);
    attn_mfma<<<dim3(16, 16, 2), dim3(512), 0, stream>>>(Qw, Kw, Vw, ik, AO);
    gemm_out<<<dim3(16, 32), dim3(256), 0, stream>>>(AO, Wot, out);
}